// Round 6
// baseline (721.476 us; speedup 1.0000x reference)
//
#include <hip/hip_runtime.h>
#include <math.h>

#define EPSV 1e-6f
#define NTOK 8192
#define NE   16384
#define DIM  256

using short8 = __attribute__((ext_vector_type(8))) short;
using f32x4v = __attribute__((ext_vector_type(4))) float;
using f32x16 = __attribute__((ext_vector_type(16))) float;

__device__ __forceinline__ unsigned short f2bf(float v) {
    unsigned int u = __float_as_uint(v);
    u += 0x7fffu + ((u >> 16) & 1u);   // RNE
    return (unsigned short)(u >> 16);
}
__device__ __forceinline__ float bf2f(unsigned short h) {
    return __uint_as_float(((unsigned int)h) << 16);
}

__device__ __forceinline__ void gload_lds16(const void* g, void* s) {
    __builtin_amdgcn_global_load_lds(
        (const __attribute__((address_space(1))) void*)g,
        (__attribute__((address_space(3))) void*)s, 16, 0, 0);
}

// split 8 consecutive fp32 into bf16 hi/lo fragments
__device__ __forceinline__ void split8(const float4 a, const float4 b,
                                       short8& h, short8& l) {
    float f[8] = {a.x, a.y, a.z, a.w, b.x, b.y, b.z, b.w};
#pragma unroll
    for (int j = 0; j < 8; ++j) {
        unsigned short hh = f2bf(f[j]);
        h[j] = (short)hh;
        l[j] = (short)f2bf(f[j] - bf2f(hh));
    }
}

// ---------------------------------------------------------------- F1:
// blocks [0,128): z transpose + bf16 split + per-token sz (fp64).
// blocks [128,192): W (256x256) bf16 hi/lo split (was k0pre).
__global__ __launch_bounds__(256) void f1_pre(
    const float* __restrict__ zin, float* __restrict__ z_flat,
    unsigned short* __restrict__ zh, unsigned short* __restrict__ zl,
    float* __restrict__ sz, const float* __restrict__ Wm,
    unsigned short* __restrict__ wh, unsigned short* __restrict__ wl) {
    const int bid = blockIdx.x;
    const int tid = threadIdx.x;
    if (bid >= 128) {                  // ---- W split
        const int i = ((bid - 128) * 256 + tid) * 4;
        const float4 v = *(const float4*)(Wm + i);
        float f[4] = {v.x, v.y, v.z, v.w};
#pragma unroll
        for (int j = 0; j < 4; ++j) {
            unsigned short h = f2bf(f[j]);
            wh[i + j] = h;
            wl[i + j] = f2bf(f[j] - bf2f(h));
        }
        return;
    }
    // ---- z transpose + split + sz
    __shared__ float tile[64][65];
    const int yx0 = (bid & 15) * 64, b = bid >> 4;
    const int sub = tid >> 6, ln = tid & 63;
    double dacc[16];
#pragma unroll
    for (int j = 0; j < 16; ++j) dacc[j] = 0.0;

    for (int cc = 0; cc < 4; ++cc) {
        const int c0 = cc * 64;
        __syncthreads();
#pragma unroll
        for (int j = 0; j < 16; ++j) {
            int cl = j * 4 + sub;
            tile[cl][ln] = zin[((size_t)(b * 256 + c0 + cl) << 10) + yx0 + ln];
        }
        __syncthreads();
#pragma unroll
        for (int j = 0; j < 16; ++j) {
            int tl = j * 4 + sub;
            float v = tile[ln][tl];
            size_t o = (size_t)(b * 1024 + yx0 + tl) * 256 + c0 + ln;
            z_flat[o] = v;
            unsigned short h = f2bf(v);
            zh[o] = h;
            zl[o] = f2bf(v - bf2f(h));
            dacc[j] += (double)v * v;
        }
    }
#pragma unroll
    for (int j = 0; j < 16; ++j) {
        double s = dacc[j];
#pragma unroll
        for (int m = 1; m < 64; m <<= 1) s += __shfl_xor(s, m);
        if (ln == 0) sz[b * 1024 + yx0 + j * 4 + sub] = (float)s;
    }
}

// ---------------------------------------------------------------- K0c:
// emb = codebook @ W.T via 4-term bf16x2 MFMA + bf16 split + per-c-tile
// se partials (fused, replaces k0d). Grid (128, 2).
__global__ __launch_bounds__(256, 2) void k0c_emb(
    const float* __restrict__ cb, const unsigned short* __restrict__ wh,
    const unsigned short* __restrict__ wl, float* __restrict__ emb,
    unsigned short* __restrict__ eh, unsigned short* __restrict__ el,
    float* __restrict__ se0, float* __restrict__ se1) {
    __shared__ char smemC[65536];
    const int tid = threadIdx.x;
    const int w = tid >> 6, lane = tid & 63;
    const int quad = lane >> 4, lr = lane & 15;
    const int wr = w & 1, wc = w >> 1;
    const int n0 = blockIdx.x * 128, c0 = blockIdx.y * 128;

    f32x4v acc[4][4];
#pragma unroll
    for (int mt = 0; mt < 4; ++mt)
#pragma unroll
        for (int nt = 0; nt < 4; ++nt)
            acc[mt][nt] = (f32x4v){0.f, 0.f, 0.f, 0.f};

    for (int kc = 0; kc < 4; ++kc) {
        __syncthreads();
#pragma unroll
        for (int i = 0; i < 16; ++i) {
            int s = i * 4 + w;           // wave-uniform segment 0..63
            int u = s * 64 + lane;       // global unit 0..4095
            const void* g;
            if (s < 32) {                // cbS: [kg(16)][row(128)] fp32x4
                int kg = u >> 7, row = u & 127;
                g = cb + (size_t)(n0 + row) * 256 + kc * 64 + kg * 4;
            } else if (s < 48) {         // whS: [kg(8)][row(128)] bf16x8
                int u1 = u - 2048;
                int kg = u1 >> 7, row = u1 & 127;
                g = wh + (size_t)(c0 + row) * 256 + kc * 64 + kg * 8;
            } else {                     // wlS
                int u2 = u - 3072;
                int kg = u2 >> 7, row = u2 & 127;
                g = wl + (size_t)(c0 + row) * 256 + kc * 64 + kg * 8;
            }
            gload_lds16(g, smemC + ((size_t)u << 4));
        }
        __syncthreads();
#pragma unroll
        for (int ks = 0; ks < 2; ++ks) {
            short8 Ah[4], Al[4], Bh[4], Bl[4];
#pragma unroll
            for (int mt = 0; mt < 4; ++mt) {
                int m = wr * 64 + mt * 16 + lr;
                int kg2 = ks * 8 + quad * 2;
                float4 f0 = *(const float4*)(smemC + (((size_t)kg2 * 128 + m) << 4));
                float4 f1 = *(const float4*)(smemC + ((((size_t)kg2 + 1) * 128 + m) << 4));
                split8(f0, f1, Ah[mt], Al[mt]);
            }
#pragma unroll
            for (int nt = 0; nt < 4; ++nt) {
                int n = wc * 64 + nt * 16 + lr;
                int ku = (ks * 4 + quad) * 128 + n;
                Bh[nt] = *(const short8*)(smemC + (((size_t)2048 + ku) << 4));
                Bl[nt] = *(const short8*)(smemC + (((size_t)3072 + ku) << 4));
            }
#pragma unroll
            for (int mt = 0; mt < 4; ++mt)
#pragma unroll
                for (int nt = 0; nt < 4; ++nt) {
                    f32x4v a = acc[mt][nt];
                    a = __builtin_amdgcn_mfma_f32_16x16x32_bf16(Ah[mt], Bh[nt], a, 0, 0, 0);
                    a = __builtin_amdgcn_mfma_f32_16x16x32_bf16(Ah[mt], Bl[nt], a, 0, 0, 0);
                    a = __builtin_amdgcn_mfma_f32_16x16x32_bf16(Al[mt], Bh[nt], a, 0, 0, 0);
                    a = __builtin_amdgcn_mfma_f32_16x16x32_bf16(Al[mt], Bl[nt], a, 0, 0, 0);
                    acc[mt][nt] = a;
                }
        }
    }
#pragma unroll
    for (int mt = 0; mt < 4; ++mt)
#pragma unroll
        for (int rr = 0; rr < 4; ++rr) {
            int row = n0 + wr * 64 + mt * 16 + quad * 4 + rr;
#pragma unroll
            for (int nt = 0; nt < 4; ++nt) {
                int col = c0 + wc * 64 + nt * 16 + lr;
                size_t o = (size_t)row * 256 + col;
                float v = acc[mt][nt][rr];
                emb[o] = v;
                unsigned short h = f2bf(v);
                eh[o] = h;
                el[o] = f2bf(v - bf2f(h));
            }
        }
    // ---- se partial over this block's 128 cols (replaces k0d)
    __syncthreads();
    float* sblk = (float*)smemC;       // [2][128]
#pragma unroll
    for (int mt = 0; mt < 4; ++mt)
#pragma unroll
        for (int rr = 0; rr < 4; ++rr) {
            float s = 0.f;
#pragma unroll
            for (int nt = 0; nt < 4; ++nt) {
                float v = acc[mt][nt][rr];
                s = fmaf(v, v, s);
            }
#pragma unroll
            for (int st = 1; st < 16; st <<= 1) s += __shfl_xor(s, st);
            if (lr == 0)
                sblk[wc * 128 + wr * 64 + mt * 16 + quad * 4 + rr] = s;
        }
    __syncthreads();
    if (tid < 128) {
        float* sep = (blockIdx.y == 0) ? se0 : se1;
        sep[n0 + tid] = sblk[tid] + sblk[128 + tid];
    }
}

// ---------------------------------------------------------------- K1:
// Fused bf16x2 (3-term) 32x32x16-MFMA GEMM + argmin.
// 512-thread blocks (8 waves) x 2 blocks/CU -> 4 waves/SIMD for latency
// hiding; one 32KB B-stage feeds 8 waves. R4's single-acc register body
// (fits the 128-VGPR step; R5's 3-chain spilled).
// Grid (NTOK/256, 16 slabs of 1024 codes). LDS 2x32KB dbuf.
__global__ __launch_bounds__(512, 4) void k1_dist_argmin(
    const unsigned short* __restrict__ zh, const unsigned short* __restrict__ zl,
    const unsigned short* __restrict__ eh, const unsigned short* __restrict__ el,
    const float* __restrict__ sz, const float* __restrict__ se0,
    const float* __restrict__ se1, float* __restrict__ pval,
    int* __restrict__ pidx) {
    __shared__ char smem[65536];       // 2 x 32 KB double buffer
    const int tid = threadIdx.x;
    const int w = tid >> 6, lane = tid & 63;
    const int col = lane & 31, half = lane >> 5;
    const int tokBase = blockIdx.x * 256;
    const int rowBase = tokBase + w * 32;
    const int slab = blockIdx.y;       // 0..15
    const int slabBase = slab * 1024;

    // A fragments: A[m=lane&31][k=half*8+j] per 16-k step. 128 VGPRs.
    short8 Ah[16], Al[16];
#pragma unroll
    for (int ks = 0; ks < 16; ++ks) {
        size_t o = (size_t)(rowBase + col) * 256 + ks * 16 + half * 8;
        Ah[ks] = *(const short8*)(zh + o);
        Al[ks] = *(const short8*)(zl + o);
    }

    // sz per C-register row: row(r) = (r&3) + 8*(r>>2) + 4*half
    float szrow[16];
#pragma unroll
    for (int r = 0; r < 16; ++r)
        szrow[r] = sz[rowBase + (r & 3) + 8 * (r >> 2) + 4 * half];

    float minv[16];
    int mini[16];
#pragma unroll
    for (int r = 0; r < 16; ++r) {
        minv[r] = INFINITY;
        mini[r] = 0;
    }

    const int BASE = col * 512 + ((half ^ (col & 1)) << 4) + ((col & 30) << 4);

    // stage chunk `ch` (32 codes x 256 k, hi+lo = 32KB) into buffer `buf`
    auto stage = [&](int buf, int ch) {
        const int colBase = slabBase + ch * 32;
#pragma unroll
        for (int i = 0; i < 4; ++i) {
            int u = i * 512 + tid;      // 0..2047
            int fmt = u >> 10;          // wave-uniform (64-aligned spans)
            int u1 = u & 1023;
            int c2 = u1 >> 5, kgs = u1 & 31;
            int kg = kgs ^ c2;          // XOR swizzle
            const unsigned short* g =
                (fmt ? el : eh) + (size_t)(colBase + c2) * 256 + kg * 8;
            gload_lds16(g, smem + buf * 32768 + ((size_t)u << 4));
        }
    };

    stage(0, 0);
    __syncthreads();

    for (int ch = 0; ch < 32; ++ch) {
        const int cur = ch & 1;
        if (ch + 1 < 32) stage(cur ^ 1, ch + 1);  // async prefetch

        const int colg = slabBase + ch * 32 + col;
        const float sec = se0[colg] + se1[colg];

        f32x16 acc = {};
        const char* sp = smem + cur * 32768;
        const char* spl = sp + 16384;
#pragma unroll
        for (int ks = 0; ks < 16; ++ks) {
            const int a = BASE ^ (ks << 5);
            short8 Bh = *(const short8*)(sp + a);
            short8 Bl = *(const short8*)(spl + a);
            acc = __builtin_amdgcn_mfma_f32_32x32x16_bf16(Ah[ks], Bh, acc, 0, 0, 0);
            acc = __builtin_amdgcn_mfma_f32_32x32x16_bf16(Ah[ks], Bl, acc, 0, 0, 0);
            acc = __builtin_amdgcn_mfma_f32_32x32x16_bf16(Al[ks], Bh, acc, 0, 0, 0);
        }

        // d = fma(-2, dot, fl(sz+se)) == fl(fl(sz+se) - 2*dot) exactly.
#pragma unroll
        for (int r = 0; r < 16; ++r) {
            float szse = __fadd_rn(szrow[r], sec);
            float d = fmaf(-2.0f, acc[r], szse);
            if (d < minv[r]) {          // strict <: first (lowest) col wins
                minv[r] = d;
                mini[r] = colg;
            }
        }
        __syncthreads();   // prefetch landed + cur consumed
    }

    // reduce across the 32 lanes (col) sharing each output row (same half)
#pragma unroll
    for (int st = 1; st < 32; st <<= 1) {
#pragma unroll
        for (int r = 0; r < 16; ++r) {
            float ov = __shfl_xor(minv[r], st);
            int oi = __shfl_xor(mini[r], st);
            if (ov < minv[r] || (ov == minv[r] && oi < mini[r])) {
                minv[r] = ov;
                mini[r] = oi;
            }
        }
    }
    if (col == 0) {
#pragma unroll
        for (int r = 0; r < 16; ++r) {
            int row = rowBase + (r & 3) + 8 * (r >> 2) + 4 * half;
            pval[(size_t)row * 16 + slab] = minv[r];
            pidx[(size_t)row * 16 + slab] = mini[r];
        }
    }
}

// ---------------------------------------------------------------- K3a:
// per-token: reduce 16 slab partials -> final index; rotation scalars;
// per-block loss partial.
__global__ __launch_bounds__(256) void k3a_token(
    const float* __restrict__ z_flat, const float* __restrict__ emb,
    const float* __restrict__ pval, const int* __restrict__ pidx,
    float* __restrict__ alpha, float* __restrict__ beta,
    int* __restrict__ idxf, float* __restrict__ out,
    float* __restrict__ lpart) {
    __shared__ float red[4];
    const int w = threadIdx.x >> 6, lane = threadIdx.x & 63;
    const int t = blockIdx.x * 4 + w;

    float bv = INFINITY;
    int bi = 0x7fffffff;
    if (lane < 16) {
        bv = pval[(size_t)t * 16 + lane];
        bi = pidx[(size_t)t * 16 + lane];
    }
#pragma unroll
    for (int st = 1; st < 16; st <<= 1) {
        float ov = __shfl_xor(bv, st);
        int oi = __shfl_xor(bi, st);
        if (ov < bv || (ov == bv && oi < bi)) { bv = ov; bi = oi; }
    }
    const int best = __shfl(bi, 0);

    const float4 zv = *(const float4*)(z_flat + (size_t)t * 256 + lane * 4);
    const float4 ev = *(const float4*)(emb + (size_t)best * 256 + lane * 4);
    float szs = zv.x * zv.x + zv.y * zv.y + zv.z * zv.z + zv.w * zv.w;
    float ses = ev.x * ev.x + ev.y * ev.y + ev.z * ev.z + ev.w * ev.w;
    float zes = zv.x * ev.x + zv.y * ev.y + zv.z * ev.z + zv.w * ev.w;
    float dx = zv.x - ev.x, dy = zv.y - ev.y, dz = zv.z - ev.z, dw = zv.w - ev.w;
    float sqs = dx * dx + dy * dy + dz * dz + dw * dw;
#pragma unroll
    for (int m = 1; m < 64; m <<= 1) {
        szs += __shfl_xor(szs, m);
        ses += __shfl_xor(ses, m);
        zes += __shfl_xor(zes, m);
        sqs += __shfl_xor(sqs, m);
    }
    if (lane == 0) {
        float ns = sqrtf(szs), nt = sqrtf(ses);
        float inv_s = 1.0f / (ns + EPSV);
        float inv_t = 1.0f / (nt + EPSV);
        float s2 = szs * inv_s;                      // z . u
        float su = szs * inv_s * inv_s;
        float sq = ses * inv_t * inv_t;
        float uq = zes * inv_s * inv_t;
        float nw = sqrtf(su + sq + 2.0f * uq);
        float inv_w = 1.0f / (nw + EPSV);
        float s1 = (s2 + zes * inv_t) * inv_w;       // z . w_
        float scale = nt * inv_s;
        float a = scale * (1.0f - 2.0f * s1 * inv_w * inv_s);
        float bb = scale * inv_t * 2.0f * (s2 - s1 * inv_w);
        alpha[t] = a;
        beta[t] = bb;
        idxf[t] = best;
        out[2097153 + t] = (float)best;
        red[w] = sqs;
    }
    __syncthreads();
    if (threadIdx.x == 0)
        lpart[blockIdx.x] = red[0] + red[1] + red[2] + red[3];
}

// ---------------------------------------------------------------- K3b:
// z_q = alpha[t]*z + beta[t]*emb[idx[t]]; block 0 also writes the loss
// (fused k4).
__global__ __launch_bounds__(256) void k3b_zq(
    const float* __restrict__ zin, const float* __restrict__ emb,
    const float* __restrict__ alpha, const float* __restrict__ beta,
    const int* __restrict__ idxf, const float* __restrict__ lpart,
    float* __restrict__ out) {
    if (blockIdx.x == 0) {             // ---- loss reduction (was k4)
        __shared__ float red[4];
        const int tid = threadIdx.x;
        float s = 0.0f;
        for (int i = tid; i < 2048; i += 256) s += lpart[i];
#pragma unroll
        for (int m = 1; m < 64; m <<= 1) s += __shfl_xor(s, m);
        if ((tid & 63) == 0) red[tid >> 6] = s;
        __syncthreads();
        if (tid == 0)
            out[2097152] = 1.25f * (red[0] + red[1] + red[2] + red[3]) *
                           (1.0f / 2097152.0f);
    }
    const int i = blockIdx.x * 256 + threadIdx.x;
    const int c = (i >> 10) & 255;
    const int t = ((i >> 18) << 10) | (i & 1023);
    out[i] = alpha[t] * zin[i] + beta[t] * emb[(size_t)idxf[t] * 256 + c];
}

// ----------------------------------------------------------------
extern "C" void kernel_launch(void* const* d_in, const int* in_sizes, int n_in,
                              void* d_out, int out_size, void* d_ws,
                              size_t ws_size, hipStream_t stream) {
    (void)in_sizes; (void)n_in; (void)out_size; (void)ws_size;
    const float* zin = (const float*)d_in[0];
    const float* cb  = (const float*)d_in[1];
    const float* Wm  = (const float*)d_in[2];
    float* out = (float*)d_out;
    char* ws = (char*)d_ws;

    float*          z_flat = (float*)(ws + 0);                     //  8 MB
    unsigned short* zh     = (unsigned short*)(ws + 8388608);      //  4 MB
    unsigned short* zl     = (unsigned short*)(ws + 12582912);     //  4 MB
    float*          emb    = (float*)(ws + 16777216);              // 16 MB
    unsigned short* eh     = (unsigned short*)(ws + 33554432);     //  8 MB
    unsigned short* el     = (unsigned short*)(ws + 41943040);     //  8 MB
    float*          sz     = (float*)(ws + 50331648);              // 32 KB
    float*          se0    = (float*)(ws + 50364416);              // 64 KB
    float*          se1    = (float*)(ws + 50429952);              // 64 KB
    float*          pval   = (float*)(ws + 50495488);              // 512 KB
    int*            pidx   = (int*)(ws + 51019776);                // 512 KB
    float*          alpha  = (float*)(ws + 51544064);              // 32 KB
    float*          beta   = (float*)(ws + 51576832);              // 32 KB
    int*            idxf   = (int*)(ws + 51609600);                // 32 KB
    float*          lpart  = (float*)(ws + 51642368);              //  8 KB
    unsigned short* wh     = (unsigned short*)(ws + 51650560);     // 128 KB
    unsigned short* wl     = (unsigned short*)(ws + 51781632);     // 128 KB

    f1_pre<<<192, 256, 0, stream>>>(zin, z_flat, zh, zl, sz, Wm, wh, wl);
    k0c_emb<<<dim3(128, 2), 256, 0, stream>>>(cb, wh, wl, emb, eh, el,
                                              se0, se1);
    k1_dist_argmin<<<dim3(32, 16), 512, 0, stream>>>(zh, zl, eh, el, sz,
                                                     se0, se1, pval, pidx);
    k3a_token<<<2048, 256, 0, stream>>>(z_flat, emb, pval, pidx, alpha, beta,
                                        idxf, out, lpart);
    k3b_zq<<<8192, 256, 0, stream>>>(zin, emb, alpha, beta, idxf, lpart, out);
}

// Round 7
// 286.667 us; speedup vs baseline: 2.5168x; 2.5168x over previous
//
#include <hip/hip_runtime.h>
#include <math.h>

#define EPSV 1e-6f
#define NTOK 8192
#define NE   16384
#define DIM  256

using short8 = __attribute__((ext_vector_type(8))) short;
using f32x4v = __attribute__((ext_vector_type(4))) float;

__device__ __forceinline__ unsigned short f2bf(float v) {
    unsigned int u = __float_as_uint(v);
    u += 0x7fffu + ((u >> 16) & 1u);   // RNE
    return (unsigned short)(u >> 16);
}
__device__ __forceinline__ float bf2f(unsigned short h) {
    return __uint_as_float(((unsigned int)h) << 16);
}

__device__ __forceinline__ void gload_lds16(const void* g, void* s) {
    __builtin_amdgcn_global_load_lds(
        (const __attribute__((address_space(1))) void*)g,
        (__attribute__((address_space(3))) void*)s, 16, 0, 0);
}

// split 8 consecutive fp32 into bf16 hi/lo fragments
__device__ __forceinline__ void split8(const float4 a, const float4 b,
                                       short8& h, short8& l) {
    float f[8] = {a.x, a.y, a.z, a.w, b.x, b.y, b.z, b.w};
#pragma unroll
    for (int j = 0; j < 8; ++j) {
        unsigned short hh = f2bf(f[j]);
        h[j] = (short)hh;
        l[j] = (short)f2bf(f[j] - bf2f(hh));
    }
}

// ---------------------------------------------------------------- F1:
// blocks [0,128): z transpose + bf16 split + per-token sz (fp64).
// blocks [128,192): W (256x256) bf16 hi/lo split.
__global__ __launch_bounds__(256) void f1_pre(
    const float* __restrict__ zin, float* __restrict__ z_flat,
    unsigned short* __restrict__ zh, unsigned short* __restrict__ zl,
    float* __restrict__ sz, const float* __restrict__ Wm,
    unsigned short* __restrict__ wh, unsigned short* __restrict__ wl) {
    const int bid = blockIdx.x;
    const int tid = threadIdx.x;
    if (bid >= 128) {                  // ---- W split
        const int i = ((bid - 128) * 256 + tid) * 4;
        const float4 v = *(const float4*)(Wm + i);
        float f[4] = {v.x, v.y, v.z, v.w};
#pragma unroll
        for (int j = 0; j < 4; ++j) {
            unsigned short h = f2bf(f[j]);
            wh[i + j] = h;
            wl[i + j] = f2bf(f[j] - bf2f(h));
        }
        return;
    }
    // ---- z transpose + split + sz
    __shared__ float tile[64][65];
    const int yx0 = (bid & 15) * 64, b = bid >> 4;
    const int sub = tid >> 6, ln = tid & 63;
    double dacc[16];
#pragma unroll
    for (int j = 0; j < 16; ++j) dacc[j] = 0.0;

    for (int cc = 0; cc < 4; ++cc) {
        const int c0 = cc * 64;
        __syncthreads();
#pragma unroll
        for (int j = 0; j < 16; ++j) {
            int cl = j * 4 + sub;
            tile[cl][ln] = zin[((size_t)(b * 256 + c0 + cl) << 10) + yx0 + ln];
        }
        __syncthreads();
#pragma unroll
        for (int j = 0; j < 16; ++j) {
            int tl = j * 4 + sub;
            float v = tile[ln][tl];
            size_t o = (size_t)(b * 1024 + yx0 + tl) * 256 + c0 + ln;
            z_flat[o] = v;
            unsigned short h = f2bf(v);
            zh[o] = h;
            zl[o] = f2bf(v - bf2f(h));
            dacc[j] += (double)v * v;
        }
    }
#pragma unroll
    for (int j = 0; j < 16; ++j) {
        double s = dacc[j];
#pragma unroll
        for (int m = 1; m < 64; m <<= 1) s += __shfl_xor(s, m);
        if (ln == 0) sz[b * 1024 + yx0 + j * 4 + sub] = (float)s;
    }
}

// ---------------------------------------------------------------- K0c:
// emb = codebook @ W.T via 4-term bf16x2 MFMA + bf16 split + per-c-tile
// se partials. Grid (128, 2).
__global__ __launch_bounds__(256, 2) void k0c_emb(
    const float* __restrict__ cb, const unsigned short* __restrict__ wh,
    const unsigned short* __restrict__ wl, float* __restrict__ emb,
    unsigned short* __restrict__ eh, unsigned short* __restrict__ el,
    float* __restrict__ se0, float* __restrict__ se1) {
    __shared__ char smemC[65536];
    const int tid = threadIdx.x;
    const int w = tid >> 6, lane = tid & 63;
    const int quad = lane >> 4, lr = lane & 15;
    const int wr = w & 1, wc = w >> 1;
    const int n0 = blockIdx.x * 128, c0 = blockIdx.y * 128;

    f32x4v acc[4][4];
#pragma unroll
    for (int mt = 0; mt < 4; ++mt)
#pragma unroll
        for (int nt = 0; nt < 4; ++nt)
            acc[mt][nt] = (f32x4v){0.f, 0.f, 0.f, 0.f};

    for (int kc = 0; kc < 4; ++kc) {
        __syncthreads();
#pragma unroll
        for (int i = 0; i < 16; ++i) {
            int s = i * 4 + w;           // wave-uniform segment 0..63
            int u = s * 64 + lane;       // global unit 0..4095
            const void* g;
            if (s < 32) {                // cbS: [kg(16)][row(128)] fp32x4
                int kg = u >> 7, row = u & 127;
                g = cb + (size_t)(n0 + row) * 256 + kc * 64 + kg * 4;
            } else if (s < 48) {         // whS: [kg(8)][row(128)] bf16x8
                int u1 = u - 2048;
                int kg = u1 >> 7, row = u1 & 127;
                g = wh + (size_t)(c0 + row) * 256 + kc * 64 + kg * 8;
            } else {                     // wlS
                int u2 = u - 3072;
                int kg = u2 >> 7, row = u2 & 127;
                g = wl + (size_t)(c0 + row) * 256 + kc * 64 + kg * 8;
            }
            gload_lds16(g, smemC + ((size_t)u << 4));
        }
        __syncthreads();
#pragma unroll
        for (int ks = 0; ks < 2; ++ks) {
            short8 Ah[4], Al[4], Bh[4], Bl[4];
#pragma unroll
            for (int mt = 0; mt < 4; ++mt) {
                int m = wr * 64 + mt * 16 + lr;
                int kg2 = ks * 8 + quad * 2;
                float4 f0 = *(const float4*)(smemC + (((size_t)kg2 * 128 + m) << 4));
                float4 f1 = *(const float4*)(smemC + ((((size_t)kg2 + 1) * 128 + m) << 4));
                split8(f0, f1, Ah[mt], Al[mt]);
            }
#pragma unroll
            for (int nt = 0; nt < 4; ++nt) {
                int n = wc * 64 + nt * 16 + lr;
                int ku = (ks * 4 + quad) * 128 + n;
                Bh[nt] = *(const short8*)(smemC + (((size_t)2048 + ku) << 4));
                Bl[nt] = *(const short8*)(smemC + (((size_t)3072 + ku) << 4));
            }
#pragma unroll
            for (int mt = 0; mt < 4; ++mt)
#pragma unroll
                for (int nt = 0; nt < 4; ++nt) {
                    f32x4v a = acc[mt][nt];
                    a = __builtin_amdgcn_mfma_f32_16x16x32_bf16(Ah[mt], Bh[nt], a, 0, 0, 0);
                    a = __builtin_amdgcn_mfma_f32_16x16x32_bf16(Ah[mt], Bl[nt], a, 0, 0, 0);
                    a = __builtin_amdgcn_mfma_f32_16x16x32_bf16(Al[mt], Bh[nt], a, 0, 0, 0);
                    a = __builtin_amdgcn_mfma_f32_16x16x32_bf16(Al[mt], Bl[nt], a, 0, 0, 0);
                    acc[mt][nt] = a;
                }
        }
    }
#pragma unroll
    for (int mt = 0; mt < 4; ++mt)
#pragma unroll
        for (int rr = 0; rr < 4; ++rr) {
            int row = n0 + wr * 64 + mt * 16 + quad * 4 + rr;
#pragma unroll
            for (int nt = 0; nt < 4; ++nt) {
                int col = c0 + wc * 64 + nt * 16 + lr;
                size_t o = (size_t)row * 256 + col;
                float v = acc[mt][nt][rr];
                emb[o] = v;
                unsigned short h = f2bf(v);
                eh[o] = h;
                el[o] = f2bf(v - bf2f(h));
            }
        }
    // ---- se partial over this block's 128 cols
    __syncthreads();
    float* sblk = (float*)smemC;       // [2][128]
#pragma unroll
    for (int mt = 0; mt < 4; ++mt)
#pragma unroll
        for (int rr = 0; rr < 4; ++rr) {
            float s = 0.f;
#pragma unroll
            for (int nt = 0; nt < 4; ++nt) {
                float v = acc[mt][nt][rr];
                s = fmaf(v, v, s);
            }
#pragma unroll
            for (int st = 1; st < 16; st <<= 1) s += __shfl_xor(s, st);
            if (lr == 0)
                sblk[wc * 128 + wr * 64 + mt * 16 + quad * 4 + rr] = s;
        }
    __syncthreads();
    if (tid < 128) {
        float* sep = (blockIdx.y == 0) ? se0 : se1;
        sep[n0 + tid] = sblk[tid] + sblk[128 + tid];
    }
}

// ---------------------------------------------------------------- K1:
// Fused bf16x2 (3-term) 16x16x32-MFMA GEMM + argmin — R2's 170.7 µs body
// (4 independent acc chains, 120 VGPR: the (256,2) 128-reg cap optimum).
// Deltas vs R2: se loads hoisted above the MFMA loop; fmaf fold
// (bit-identical rounding).
// Grid (NTOK/128, 8 slabs). 4 waves; wave w owns rows [tokBase+w*32,+32).
__global__ __launch_bounds__(256, 2) void k1_dist_argmin(
    const unsigned short* __restrict__ zh, const unsigned short* __restrict__ zl,
    const unsigned short* __restrict__ eh, const unsigned short* __restrict__ el,
    const float* __restrict__ sz, const float* __restrict__ se0,
    const float* __restrict__ se1, float* __restrict__ pval,
    int* __restrict__ pidx) {
    __shared__ short8 smem[2][2048];   // 2 x 32 KB
    const int tid = threadIdx.x;
    const int w = tid >> 6, lane = tid & 63;
    const int quad = lane >> 4, lr = lane & 15;
    const int tokBase = blockIdx.x * 128;
    const int rowBase = tokBase + w * 32;
    const int slab = blockIdx.y;
    const int slabBase = slab * 2048;

    // A fragments resident for the whole kernel (128 VGPRs)
    short8 Ah[2][8], Al[2][8];
#pragma unroll
    for (int mt = 0; mt < 2; ++mt)
#pragma unroll
        for (int ks = 0; ks < 8; ++ks) {
            size_t o = (size_t)(rowBase + mt * 16 + lr) * 256 + ks * 32 + quad * 8;
            Ah[mt][ks] = *(const short8*)(zh + o);
            Al[mt][ks] = *(const short8*)(zl + o);
        }

    float szr[2][4];
#pragma unroll
    for (int mt = 0; mt < 2; ++mt)
#pragma unroll
        for (int rr = 0; rr < 4; ++rr)
            szr[mt][rr] = sz[rowBase + mt * 16 + quad * 4 + rr];

    float minv[2][4];
    int mini[2][4];
#pragma unroll
    for (int mt = 0; mt < 2; ++mt)
#pragma unroll
        for (int rr = 0; rr < 4; ++rr) {
            minv[mt][rr] = INFINITY;
            mini[mt][rr] = 0;
        }

    // stage chunk `ch` (32 codes x 256 k, hi+lo) into buffer `buf`
    auto stage = [&](int buf, int ch) {
        const int colBase = slabBase + ch * 32;
#pragma unroll
        for (int i = 0; i < 8; ++i) {
            int u = i * 256 + tid;      // 0..2047
            int fmt = u >> 10;          // wave-uniform
            int u1 = u & 1023;
            int col = u1 >> 5, kgs = u1 & 31;
            int kg = kgs ^ col;         // XOR swizzle
            const unsigned short* g =
                (fmt ? el : eh) + (size_t)(colBase + col) * 256 + kg * 8;
            gload_lds16(g, (char*)&smem[0][0] + buf * 32768 +
                               (((size_t)i * 256 + w * 64) << 4));
        }
    };

    stage(0, 0);
    __syncthreads();

    for (int ch = 0; ch < 64; ++ch) {
        const int cur = ch & 1;
        if (ch + 1 < 64) stage(cur ^ 1, ch + 1);  // async prefetch

        // hoist se loads: ~200cy L2 latency hidden under the MFMA burst
        const int colg0 = slabBase + ch * 32 + lr;
        const int colg1 = colg0 + 16;
        const float sec0 = se0[colg0] + se1[colg0];
        const float sec1 = se0[colg1] + se1[colg1];

        f32x4v acc[2][2];
#pragma unroll
        for (int mt = 0; mt < 2; ++mt)
#pragma unroll
            for (int nt = 0; nt < 2; ++nt)
                acc[mt][nt] = (f32x4v){0.f, 0.f, 0.f, 0.f};

#pragma unroll
        for (int ks = 0; ks < 8; ++ks) {
            short8 Bh[2], Bl[2];
#pragma unroll
            for (int nt = 0; nt < 2; ++nt) {
                int col = nt * 16 + lr;
                int kgs = (ks * 4 + quad) ^ col;
                Bh[nt] = smem[cur][col * 32 + kgs];
                Bl[nt] = smem[cur][1024 + col * 32 + kgs];
            }
#pragma unroll
            for (int mt = 0; mt < 2; ++mt)
#pragma unroll
                for (int nt = 0; nt < 2; ++nt) {
                    f32x4v a = acc[mt][nt];
                    a = __builtin_amdgcn_mfma_f32_16x16x32_bf16(Ah[mt][ks], Bh[nt], a, 0, 0, 0);
                    a = __builtin_amdgcn_mfma_f32_16x16x32_bf16(Ah[mt][ks], Bl[nt], a, 0, 0, 0);
                    a = __builtin_amdgcn_mfma_f32_16x16x32_bf16(Al[mt][ks], Bh[nt], a, 0, 0, 0);
                    acc[mt][nt] = a;
                }
        }

        // d = fma(-2, dot, fl(sz+se)) == fl(fl(sz+se) - 2*dot) exactly
        const int colBase = slabBase + ch * 32;
#pragma unroll
        for (int nt = 0; nt < 2; ++nt) {
            const int colg = colBase + nt * 16 + lr;
            const float sec = nt ? sec1 : sec0;
#pragma unroll
            for (int mt = 0; mt < 2; ++mt)
#pragma unroll
                for (int rr = 0; rr < 4; ++rr) {
                    float szse = __fadd_rn(szr[mt][rr], sec);
                    float d = fmaf(-2.0f, acc[mt][nt][rr], szse);
                    if (d < minv[mt][rr]) {   // strict <: first index wins
                        minv[mt][rr] = d;
                        mini[mt][rr] = colg;
                    }
                }
        }
        __syncthreads();   // prefetch landed + cur consumed
    }

    // reduce across the 16 lanes (lr) that share each output row
#pragma unroll
    for (int st = 1; st < 16; st <<= 1) {
#pragma unroll
        for (int mt = 0; mt < 2; ++mt)
#pragma unroll
            for (int rr = 0; rr < 4; ++rr) {
                float ov = __shfl_xor(minv[mt][rr], st);
                int oi = __shfl_xor(mini[mt][rr], st);
                if (ov < minv[mt][rr] ||
                    (ov == minv[mt][rr] && oi < mini[mt][rr])) {
                    minv[mt][rr] = ov;
                    mini[mt][rr] = oi;
                }
            }
    }
    if (lr == 0) {
#pragma unroll
        for (int mt = 0; mt < 2; ++mt)
#pragma unroll
            for (int rr = 0; rr < 4; ++rr) {
                int row = rowBase + mt * 16 + quad * 4 + rr;
                pval[(size_t)row * 8 + slab] = minv[mt][rr];
                pidx[(size_t)row * 8 + slab] = mini[mt][rr];
            }
    }
}

// ---------------------------------------------------------------- K3a:
// per-token: reduce 8 slab partials -> final index; rotation scalars;
// per-block loss partial.
__global__ __launch_bounds__(256) void k3a_token(
    const float* __restrict__ z_flat, const float* __restrict__ emb,
    const float* __restrict__ pval, const int* __restrict__ pidx,
    float* __restrict__ alpha, float* __restrict__ beta,
    int* __restrict__ idxf, float* __restrict__ out,
    float* __restrict__ lpart) {
    __shared__ float red[4];
    const int w = threadIdx.x >> 6, lane = threadIdx.x & 63;
    const int t = blockIdx.x * 4 + w;

    float bv = INFINITY;
    int bi = 0x7fffffff;
    if (lane < 8) {
        bv = pval[(size_t)t * 8 + lane];
        bi = pidx[(size_t)t * 8 + lane];
    }
#pragma unroll
    for (int st = 1; st < 8; st <<= 1) {
        float ov = __shfl_xor(bv, st);
        int oi = __shfl_xor(bi, st);
        if (ov < bv || (ov == bv && oi < bi)) { bv = ov; bi = oi; }
    }
    const int best = __shfl(bi, 0);

    const float4 zv = *(const float4*)(z_flat + (size_t)t * 256 + lane * 4);
    const float4 ev = *(const float4*)(emb + (size_t)best * 256 + lane * 4);
    float szs = zv.x * zv.x + zv.y * zv.y + zv.z * zv.z + zv.w * zv.w;
    float ses = ev.x * ev.x + ev.y * ev.y + ev.z * ev.z + ev.w * ev.w;
    float zes = zv.x * ev.x + zv.y * ev.y + zv.z * ev.z + zv.w * ev.w;
    float dx = zv.x - ev.x, dy = zv.y - ev.y, dz = zv.z - ev.z, dw = zv.w - ev.w;
    float sqs = dx * dx + dy * dy + dz * dz + dw * dw;
#pragma unroll
    for (int m = 1; m < 64; m <<= 1) {
        szs += __shfl_xor(szs, m);
        ses += __shfl_xor(ses, m);
        zes += __shfl_xor(zes, m);
        sqs += __shfl_xor(sqs, m);
    }
    if (lane == 0) {
        float ns = sqrtf(szs), nt = sqrtf(ses);
        float inv_s = 1.0f / (ns + EPSV);
        float inv_t = 1.0f / (nt + EPSV);
        float s2 = szs * inv_s;                      // z . u
        float su = szs * inv_s * inv_s;
        float sq = ses * inv_t * inv_t;
        float uq = zes * inv_s * inv_t;
        float nw = sqrtf(su + sq + 2.0f * uq);
        float inv_w = 1.0f / (nw + EPSV);
        float s1 = (s2 + zes * inv_t) * inv_w;       // z . w_
        float scale = nt * inv_s;
        float a = scale * (1.0f - 2.0f * s1 * inv_w * inv_s);
        float bb = scale * inv_t * 2.0f * (s2 - s1 * inv_w);
        alpha[t] = a;
        beta[t] = bb;
        idxf[t] = best;
        out[2097153 + t] = (float)best;
        red[w] = sqs;
    }
    __syncthreads();
    if (threadIdx.x == 0)
        lpart[blockIdx.x] = red[0] + red[1] + red[2] + red[3];
}

// ---------------------------------------------------------------- K3b:
// z_q = alpha[t]*z + beta[t]*emb[idx[t]]; block 0 also writes the loss.
__global__ __launch_bounds__(256) void k3b_zq(
    const float* __restrict__ zin, const float* __restrict__ emb,
    const float* __restrict__ alpha, const float* __restrict__ beta,
    const int* __restrict__ idxf, const float* __restrict__ lpart,
    float* __restrict__ out) {
    if (blockIdx.x == 0) {             // ---- loss reduction
        __shared__ float red[4];
        const int tid = threadIdx.x;
        float s = 0.0f;
        for (int i = tid; i < 2048; i += 256) s += lpart[i];
#pragma unroll
        for (int m = 1; m < 64; m <<= 1) s += __shfl_xor(s, m);
        if ((tid & 63) == 0) red[tid >> 6] = s;
        __syncthreads();
        if (tid == 0)
            out[2097152] = 1.25f * (red[0] + red[1] + red[2] + red[3]) *
                           (1.0f / 2097152.0f);
    }
    const int i = blockIdx.x * 256 + threadIdx.x;
    const int c = (i >> 10) & 255;
    const int t = ((i >> 18) << 10) | (i & 1023);
    out[i] = alpha[t] * zin[i] + beta[t] * emb[(size_t)idxf[t] * 256 + c];
}

// ----------------------------------------------------------------
extern "C" void kernel_launch(void* const* d_in, const int* in_sizes, int n_in,
                              void* d_out, int out_size, void* d_ws,
                              size_t ws_size, hipStream_t stream) {
    (void)in_sizes; (void)n_in; (void)out_size; (void)ws_size;
    const float* zin = (const float*)d_in[0];
    const float* cb  = (const float*)d_in[1];
    const float* Wm  = (const float*)d_in[2];
    float* out = (float*)d_out;
    char* ws = (char*)d_ws;

    float*          z_flat = (float*)(ws + 0);                     //  8 MB
    unsigned short* zh     = (unsigned short*)(ws + 8388608);      //  4 MB
    unsigned short* zl     = (unsigned short*)(ws + 12582912);     //  4 MB
    float*          emb    = (float*)(ws + 16777216);              // 16 MB
    unsigned short* eh     = (unsigned short*)(ws + 33554432);     //  8 MB
    unsigned short* el     = (unsigned short*)(ws + 41943040);     //  8 MB
    float*          sz     = (float*)(ws + 50331648);              // 32 KB
    float*          se0    = (float*)(ws + 50364416);              // 64 KB
    float*          se1    = (float*)(ws + 50429952);              // 64 KB
    float*          pval   = (float*)(ws + 50495488);              // 256 KB
    int*            pidx   = (int*)(ws + 50757632);                // 256 KB
    float*          alpha  = (float*)(ws + 51019776);              // 32 KB
    float*          beta   = (float*)(ws + 51052544);              // 32 KB
    int*            idxf   = (int*)(ws + 51085312);                // 32 KB
    float*          lpart  = (float*)(ws + 51118080);              //  8 KB
    unsigned short* wh     = (unsigned short*)(ws + 51126272);     // 128 KB
    unsigned short* wl     = (unsigned short*)(ws + 51257344);     // 128 KB

    f1_pre<<<192, 256, 0, stream>>>(zin, z_flat, zh, zl, sz, Wm, wh, wl);
    k0c_emb<<<dim3(128, 2), 256, 0, stream>>>(cb, wh, wl, emb, eh, el,
                                              se0, se1);
    k1_dist_argmin<<<dim3(64, 8), 256, 0, stream>>>(zh, zl, eh, el, sz,
                                                    se0, se1, pval, pidx);
    k3a_token<<<2048, 256, 0, stream>>>(z_flat, emb, pval, pidx, alpha, beta,
                                        idxf, out, lpart);
    k3b_zq<<<8192, 256, 0, stream>>>(zin, emb, alpha, beta, idxf, lpart, out);
}